// Round 15
// baseline (215.214 us; speedup 1.0000x reference)
//
#include <hip/hip_runtime.h>
#include <hip/hip_bf16.h>

typedef __attribute__((ext_vector_type(8))) short short8;
typedef __attribute__((ext_vector_type(4))) float f32x4;

#define NDIM 1024
#define INDIM 1024
#define KEXP 8
#define BROWS 8192
#define NX (BROWS * INDIM)        // x elements   8388608
#define NW (KEXP * NDIM * INDIM)  // w elements   8388608

__device__ __forceinline__ unsigned int pack2bf(float a, float b) {
    __hip_bfloat162 h = __float22bfloat162_rn(make_float2(a, b));
    union { __hip_bfloat162 h; unsigned int u; } cv;
    cv.h = h;
    return cv.u;
}

__device__ __forceinline__ void gload16(const void* src, void* ldsdst) {
    __builtin_amdgcn_global_load_lds(
        (__attribute__((address_space(1))) void*)(src),
        (__attribute__((address_space(3))) void*)(ldsdst), 16, 0, 0);
}

// convert: ws = [bf16(x) | bf16(w)] contiguous
__global__ void convert_bf16(const float* __restrict__ x, const float* __restrict__ w,
                             unsigned short* __restrict__ dst) {
    const long total = (long)NX + NW;
    const long stride = (long)gridDim.x * blockDim.x * 8;
    for (long i = ((long)blockIdx.x * blockDim.x + threadIdx.x) * 8; i < total; i += stride) {
        const float* s = (i < NX) ? (x + i) : (w + (i - NX));
        float4 a = ((const float4*)s)[0];
        float4 b = ((const float4*)s)[1];
        uint4 q;
        q.x = pack2bf(a.x, a.y); q.y = pack2bf(a.z, a.w);
        q.z = pack2bf(b.x, b.y); q.w = pack2bf(b.z, b.w);
        *(uint4*)(dst + i) = q;
    }
}

// Persistent transposed-M fused GEMM+blend.
// grid 256 = 1 block/CU: 32 bt x 8 ogrp (bid&7 = XCD pins the 2MB x-slice).
// Each block runs ONE continuous 64-tile dbuf pipeline over 4 o-tiles (staging
// address switches o-tile every 16 tiles; no refill). Per-o-tile epilogue uses
// a SEPARATE 32KB ylds region (staging untouched): k-blend in f32 (4 FMA +
// shfl_xor(16)), XOR-swizzled transpose, exact ew@bias, coalesced float4 store.
// LDS total = 128K staging + 32K ylds = 160 KiB exactly.
__global__ __launch_bounds__(512, 2)
void moe_gemm_pf(const unsigned short* __restrict__ xb,   // [8192][1024] bf16
                 const float* __restrict__ ew,            // [8192][8]
                 const unsigned short* __restrict__ Wp,   // [8][1024][1024] bf16
                 const float* __restrict__ bias,          // [8][1024]
                 float* __restrict__ out) {               // [8192][1024] f32
    __shared__ __align__(16) unsigned short lds[2 * 32768];   // 128 KiB dbuf
    __shared__ __align__(16) float ylds[8192];                // 32 KiB transpose buf

    const int tid = threadIdx.x;
    const int bid = blockIdx.x;
    const int xcd = bid & 7;
    const int bt = xcd * 4 + ((bid >> 3) & 3);   // 0..31 b-tile (XCD-pinned x)
    const int ogrp = bid >> 5;                   // 0..7
    const int bbase = bt * 256;
    const int o_base = ogrp * 128;               // covers 4 o-tiles of 32

    const int w  = tid >> 6;           // wave 0..7 (2M x 4N), wave tile 128x64
    const int l  = tid & 63;
    const int lr = l & 15;
    const int lg = l >> 4;
    const int wrow = (w >> 2) * 128;
    const int wcol = (w & 3) * 64;

    // staging lane coords: chunk = 16 rows x 32 cols bf16 = 1024 B
    const int lrow = l >> 2;
    const int sg = (l & 3) ^ ((l >> 3) & 3);     // pre-swizzled col block (involution)
    const int swz = (lr >> 1) & 3;

    // fragment read offsets (ushort units), matching XOR involution
    int aoff[8][2], boff[4][2];
#pragma unroll
    for (int mf = 0; mf < 8; ++mf)
#pragma unroll
        for (int ks = 0; ks < 2; ++ks)
            aoff[mf][ks] = ks * 8192 + (wrow + mf * 16 + lr) * 32 + ((lg ^ swz) * 8);
#pragma unroll
    for (int nf = 0; nf < 4; ++nf)
#pragma unroll
        for (int ks = 0; ks < 2; ++ks)
            boff[nf][ks] = 16384 + ks * 8192 + (wcol + nf * 16 + lr) * 32 + ((lg ^ swz) * 8);

    // staging for global tile g (0..63): o-tile g>>4, K-col (g&15)*64
    auto stage4 = [&](int slot, int g, int half) {
        const int o_blk_s = o_base + (g >> 4) * 32;
        const int kcol = (g & 15) * 64;
#pragma unroll
        for (int i = 0; i < 4; ++i) {
            const int id = w * 8 + half * 4 + i;
            unsigned short* dst = &lds[slot * 32768 + id * 512];
            const int sub = id & 15;
            const int col = kcol + ((id >> 4) & 1) * 32 + sg * 8;
            if (id < 32) {
                // gathered row: ke = lrow&7, o = o_blk_s + sub*2 + (lrow>>3)
                gload16(Wp + (size_t)(lrow & 7) * (NDIM * INDIM)
                           + (size_t)(o_blk_s + sub * 2 + (lrow >> 3)) * INDIM + col, dst);
            } else {
                gload16(xb + (size_t)(bbase + sub * 16 + lrow) * INDIM + col, dst);
            }
        }
    };

    f32x4 acc[8][4];
#pragma unroll
    for (int mf = 0; mf < 8; ++mf)
#pragma unroll
        for (int nf = 0; nf < 4; ++nf) acc[mf][nf] = f32x4{0.f, 0.f, 0.f, 0.f};

    stage4(0, 0, 0);
    stage4(0, 0, 1);

#pragma unroll 1
    for (int g = 0; g < 64; ++g) {
        const int cs = g & 1;
        const bool doS = (g + 1) < 64;

        // tile gate: stage(g) landed (also drains prior epilogue stores);
        // barrier publishes all waves' staging AND separates ylds read/write.
        asm volatile("s_waitcnt vmcnt(0)\n\ts_barrier" ::: "memory");

        const unsigned short* lb = &lds[cs * 32768];
        short8 alo[4], ahi[4], b0[4], b1[4];

        // q0 operands + first staging batch + q1 A-frags (drain under q0 MFMA)
#pragma unroll
        for (int m = 0; m < 4; ++m) alo[m] = *(const short8*)(lb + aoff[m][0]);
#pragma unroll
        for (int n = 0; n < 4; ++n) b0[n] = *(const short8*)(lb + boff[n][0]);
        if (doS) stage4(cs ^ 1, g + 1, 0);
#pragma unroll
        for (int m = 0; m < 4; ++m) ahi[m] = *(const short8*)(lb + aoff[4 + m][0]);

        __builtin_amdgcn_s_setprio(1);
#pragma unroll
        for (int m = 0; m < 4; ++m)
#pragma unroll
            for (int n = 0; n < 4; ++n)
                acc[m][n] = __builtin_amdgcn_mfma_f32_16x16x32_bf16(alo[m], b0[n], acc[m][n], 0, 0, 0);
        __builtin_amdgcn_s_setprio(0);

        // q2 operands (ks1) issued now; second staging batch
#pragma unroll
        for (int n = 0; n < 4; ++n) b1[n] = *(const short8*)(lb + boff[n][1]);
#pragma unroll
        for (int m = 0; m < 4; ++m) alo[m] = *(const short8*)(lb + aoff[m][1]);
        if (doS) stage4(cs ^ 1, g + 1, 1);

        __builtin_amdgcn_s_setprio(1);
#pragma unroll
        for (int m = 0; m < 4; ++m)
#pragma unroll
            for (int n = 0; n < 4; ++n)
                acc[4 + m][n] = __builtin_amdgcn_mfma_f32_16x16x32_bf16(ahi[m], b0[n], acc[4 + m][n], 0, 0, 0);
        __builtin_amdgcn_s_setprio(0);

#pragma unroll
        for (int m = 0; m < 4; ++m) ahi[m] = *(const short8*)(lb + aoff[4 + m][1]);

        __builtin_amdgcn_s_setprio(1);
#pragma unroll
        for (int m = 0; m < 4; ++m)
#pragma unroll
            for (int n = 0; n < 4; ++n)
                acc[m][n] = __builtin_amdgcn_mfma_f32_16x16x32_bf16(alo[m], b1[n], acc[m][n], 0, 0, 0);
        __builtin_amdgcn_s_setprio(0);

        __builtin_amdgcn_s_setprio(1);
#pragma unroll
        for (int m = 0; m < 4; ++m)
#pragma unroll
            for (int n = 0; n < 4; ++n)
                acc[4 + m][n] = __builtin_amdgcn_mfma_f32_16x16x32_bf16(ahi[m], b1[n], acc[4 + m][n], 0, 0, 0);
        __builtin_amdgcn_s_setprio(0);

        // ---- o-tile boundary epilogue (ylds is separate; staging unaffected) ----
        // C/D map: frag row = lg*4 + j -> g_row = wrow + mf*16 + lg*4 + j
        //          -> o = o_blk + (g_row>>3), k = g_row&7 = (lg&1)*4 + j
        if ((g & 15) == 15) {
            const int o_blk = o_base + (g >> 4) * 32;
            const int obw = wrow >> 3;               // wave o-offset: 0 or 16
            // phys(b, ol) = b*32 + (ol ^ (4*(b&7))): writes/reads ~2-way max,
            // float4-aligned (XOR operand multiple of 4).
#pragma unroll
            for (int nf = 0; nf < 4; ++nf) {
                const int bl = wcol + nf * 16 + lr;          // block-local b
                const int bsw = 4 * (bl & 7);
                const float4 ea = *(const float4*)(ew + (size_t)(bbase + bl) * KEXP);
                const float4 eb = *(const float4*)(ew + (size_t)(bbase + bl) * KEXP + 4);
                float c0, c1, c2, c3;
                if (lg & 1) { c0 = eb.x; c1 = eb.y; c2 = eb.z; c3 = eb.w; }
                else        { c0 = ea.x; c1 = ea.y; c2 = ea.z; c3 = ea.w; }
#pragma unroll
                for (int mf = 0; mf < 8; ++mf) {
                    float p = c0 * acc[mf][nf][0] + c1 * acc[mf][nf][1]
                            + c2 * acc[mf][nf][2] + c3 * acc[mf][nf][3];
                    p += __shfl_xor(p, 16);                  // sum k 0-3 with k 4-7
                    if (!(lg & 1)) {
                        const int ol = obw + mf * 2 + (lg >> 1);
                        ylds[bl * 32 + (ol ^ bsw)] = p;
                    }
                    acc[mf][nf] = f32x4{0.f, 0.f, 0.f, 0.f};
                }
            }
            __syncthreads();

            {   // coalesced f32 store + exact ew@bias
                const int b = tid >> 1;
                const int oh = (tid & 1) * 16;
                const int sw = 4 * (b & 7);
                const float* yr = &ylds[b * 32];
                float y0[16];
#pragma unroll
                for (int q = 0; q < 4; ++q) {
                    const float4 v = *(const float4*)(yr + ((oh + q * 4) ^ sw));
                    y0[q * 4 + 0] = v.x; y0[q * 4 + 1] = v.y;
                    y0[q * 4 + 2] = v.z; y0[q * 4 + 3] = v.w;
                }
                const float4 ea = *(const float4*)(ew + (size_t)(bbase + b) * KEXP);
                const float4 e2 = *(const float4*)(ew + (size_t)(bbase + b) * KEXP + 4);
                const float ekk[8] = {ea.x, ea.y, ea.z, ea.w, e2.x, e2.y, e2.z, e2.w};
#pragma unroll
                for (int k = 0; k < 8; ++k) {
                    const float* bp = bias + k * NDIM + o_blk + oh;
#pragma unroll
                    for (int jj = 0; jj < 16; ++jj) y0[jj] += ekk[k] * bp[jj];
                }
                float* op = out + (size_t)(bbase + b) * NDIM + o_blk + oh;
#pragma unroll
                for (int jj = 0; jj < 4; ++jj)
                    *(float4*)(op + jj * 4) =
                        make_float4(y0[jj * 4], y0[jj * 4 + 1], y0[jj * 4 + 2], y0[jj * 4 + 3]);
            }
            // next tile-gate barrier separates these ylds reads from the next
            // o-tile's ylds writes (16 tiles away) — no extra barrier needed.
        }
    }
}

// ---------------- fallback (round-1 kernel, needs NO workspace) ----------------
#define FLDW 40
__global__ __launch_bounds__(256, 2)
void moe_blend_gemm_fb(const float* __restrict__ x, const float* __restrict__ ew,
                       const float* __restrict__ w, const float* __restrict__ bias,
                       float* __restrict__ out) {
    __shared__ unsigned short lA[128][FLDW];
    __shared__ unsigned short lB[128][FLDW];
    const int tid = threadIdx.x, bid = blockIdx.x;
    const int nt = bid & 7, mt = bid >> 3;
    const int mbase = mt * 128, nbase = nt * 128;
    const int trow = tid >> 1, tcol = (tid & 1) * 16;
    const float* xp = x + (size_t)(mbase + trow) * INDIM + tcol;
    const float* wp = w + (size_t)(nbase + trow) * INDIM + tcol;
    const float* ep = ew + (size_t)(mbase + trow) * KEXP;
    const int wid = tid >> 6, wrB = (wid >> 1) * 64, wcB = (wid & 1) * 64;
    const int l = tid & 63, lr = l & 15, lg = l >> 4;
    f32x4 acc[4][4];
#pragma unroll
    for (int m = 0; m < 4; ++m)
#pragma unroll
        for (int n = 0; n < 4; ++n) acc[m][n] = f32x4{0.f, 0.f, 0.f, 0.f};
    const unsigned short* rdA = &lA[wrB + lr][lg * 8];
    const unsigned short* rdB = &lB[wcB + lr][lg * 8];
    unsigned int* wA = (unsigned int*)&lA[trow][tcol];
    unsigned int* wB = (unsigned int*)&lB[trow][tcol];
    float4 ra0, ra1, ra2, ra3, rb0, rb1, rb2, rb3;
    float sc;
    {
        const float4* pa = (const float4*)(xp);
        ra0 = pa[0]; ra1 = pa[1]; ra2 = pa[2]; ra3 = pa[3];
        const float4* pb = (const float4*)(wp);
        rb0 = pb[0]; rb1 = pb[1]; rb2 = pb[2]; rb3 = pb[3];
        sc = ep[0];
    }
    for (int tt = 0; tt < 256; ++tt) {
        __syncthreads();
        uint4 qa0, qa1, qb0, qb1;
        qa0.x = pack2bf(ra0.x * sc, ra0.y * sc); qa0.y = pack2bf(ra0.z * sc, ra0.w * sc);
        qa0.z = pack2bf(ra1.x * sc, ra1.y * sc); qa0.w = pack2bf(ra1.z * sc, ra1.w * sc);
        qa1.x = pack2bf(ra2.x * sc, ra2.y * sc); qa1.y = pack2bf(ra2.z * sc, ra2.w * sc);
        qa1.z = pack2bf(ra3.x * sc, ra3.y * sc); qa1.w = pack2bf(ra3.z * sc, ra3.w * sc);
        qb0.x = pack2bf(rb0.x, rb0.y); qb0.y = pack2bf(rb0.z, rb0.w);
        qb0.z = pack2bf(rb1.x, rb1.y); qb0.w = pack2bf(rb1.z, rb1.w);
        qb1.x = pack2bf(rb2.x, rb2.y); qb1.y = pack2bf(rb2.z, rb2.w);
        qb1.z = pack2bf(rb3.x, rb3.y); qb1.w = pack2bf(rb3.z, rb3.w);
        *(uint4*)(wA) = qa0; *(uint4*)(wA + 4) = qa1;
        *(uint4*)(wB) = qb0; *(uint4*)(wB + 4) = qb1;
        __syncthreads();
        if (tt + 1 < 256) {
            const int kc = (tt + 1) >> 5, i0 = ((tt + 1) & 31) * 32;
            const float4* pa = (const float4*)(xp + i0);
            ra0 = pa[0]; ra1 = pa[1]; ra2 = pa[2]; ra3 = pa[3];
            const float4* pb = (const float4*)(wp + (size_t)kc * (size_t)(NDIM * INDIM) + i0);
            rb0 = pb[0]; rb1 = pb[1]; rb2 = pb[2]; rb3 = pb[3];
            sc = ep[kc];
        }
        short8 af[4], bf[4];
#pragma unroll
        for (int m = 0; m < 4; ++m) af[m] = *(const short8*)(rdA + m * 16 * FLDW);
#pragma unroll
        for (int n = 0; n < 4; ++n) bf[n] = *(const short8*)(rdB + n * 16 * FLDW);
#pragma unroll
        for (int m = 0; m < 4; ++m)
#pragma unroll
            for (int n = 0; n < 4; ++n)
                acc[m][n] = __builtin_amdgcn_mfma_f32_16x16x32_bf16(af[m], bf[n], acc[m][n], 0, 0, 0);
    }
#pragma unroll
    for (int m = 0; m < 4; ++m)
#pragma unroll
        for (int j = 0; j < 4; ++j) {
            const int gr = mbase + wrB + m * 16 + lg * 4 + j;
            const float4* e4 = (const float4*)(ew + (size_t)gr * KEXP);
            const float4 e0 = e4[0], e1 = e4[1];
            const float eb[8] = {e0.x, e0.y, e0.z, e0.w, e1.x, e1.y, e1.z, e1.w};
            float* op = out + (size_t)gr * NDIM + nbase + wcB;
#pragma unroll
            for (int n = 0; n < 4; ++n) {
                float t = acc[m][n][j];
#pragma unroll
                for (int kk = 0; kk < 8; ++kk) t += eb[kk] * bias[kk * NDIM + nbase + wcB + n * 16 + lr];
                op[n * 16 + lr] = t;
            }
        }
}

extern "C" void kernel_launch(void* const* d_in, const int* in_sizes, int n_in,
                              void* d_out, int out_size, void* d_ws, size_t ws_size,
                              hipStream_t stream) {
    (void)in_sizes; (void)n_in; (void)out_size;
    const float* x    = (const float*)d_in[0];
    const float* ew   = (const float*)d_in[1];
    const float* w    = (const float*)d_in[2];
    const float* bias = (const float*)d_in[3];
    float* out = (float*)d_out;

    const size_t need = (size_t)(NX + NW) * sizeof(unsigned short);   // 33.5 MB

    if (ws_size >= need) {
        unsigned short* xb = (unsigned short*)d_ws;
        unsigned short* Wp = xb + NX;
        hipLaunchKernelGGL(convert_bf16, dim3(4096), dim3(256), 0, stream, x, w, xb);
        hipLaunchKernelGGL(moe_gemm_pf, dim3(256), dim3(512), 0, stream, xb, ew, Wp, bias, out);
    } else {
        hipLaunchKernelGGL(moe_blend_gemm_fb, dim3(512), dim3(256), 0, stream, x, ew, w, bias, out);
    }
}

// Round 16
// 145.856 us; speedup vs baseline: 1.4755x; 1.4755x over previous
//
#include <hip/hip_runtime.h>
#include <hip/hip_bf16.h>

typedef __attribute__((ext_vector_type(8))) short short8;
typedef __attribute__((ext_vector_type(4))) float f32x4;

#define NDIM 1024
#define INDIM 1024
#define KEXP 8
#define BROWS 8192
#define NX (BROWS * INDIM)        // x elements   8388608
#define NW (KEXP * NDIM * INDIM)  // w elements   8388608

__device__ __forceinline__ unsigned int pack2bf(float a, float b) {
    __hip_bfloat162 h = __float22bfloat162_rn(make_float2(a, b));
    union { __hip_bfloat162 h; unsigned int u; } cv;
    cv.h = h;
    return cv.u;
}

__device__ __forceinline__ void gload16(const void* src, void* ldsdst) {
    __builtin_amdgcn_global_load_lds(
        (__attribute__((address_space(1))) void*)(src),
        (__attribute__((address_space(3))) void*)(ldsdst), 16, 0, 0);
}

// convert: ws = [bf16(x) | bf16(w)] contiguous
__global__ void convert_bf16(const float* __restrict__ x, const float* __restrict__ w,
                             unsigned short* __restrict__ dst) {
    const long total = (long)NX + NW;
    const long stride = (long)gridDim.x * blockDim.x * 8;
    for (long i = ((long)blockIdx.x * blockDim.x + threadIdx.x) * 8; i < total; i += stride) {
        const float* s = (i < NX) ? (x + i) : (w + (i - NX));
        float4 a = ((const float4*)s)[0];
        float4 b = ((const float4*)s)[1];
        uint4 q;
        q.x = pack2bf(a.x, a.y); q.y = pack2bf(a.z, a.w);
        q.z = pack2bf(b.x, b.y); q.w = pack2bf(b.z, b.w);
        *(uint4*)(dst + i) = q;
    }
}

// Transposed-M fused GEMM+blend (session-best r12 structure).
// M = gathered (o,k): block tile = 32 o x 8 experts = 256 rows
// (g = (o-o0)*8 + k, so ke = lrow&7 per-lane-constant in staging).
// C[g,b] = sum_i W[ke,o,i]*x[b,i]; epilogue does the k-blend in f32 (4 FMA +
// shfl_xor(16) per frag), LDS-transposes, adds exact ew@bias, stores f32 out.
// Schedule/geometry = r5's verified kernel: 256x256, BK=64, 8 waves of 128x64,
// dbuf-2 LDS, vmcnt(0)+barrier gate per tile, XOR-swizzled staging.
__global__ __launch_bounds__(512, 2)
void moe_gemm_fold(const unsigned short* __restrict__ xb,   // [8192][1024] bf16
                   const float* __restrict__ ew,            // [8192][8]
                   const unsigned short* __restrict__ Wp,   // [8][1024][1024] bf16
                   const float* __restrict__ bias,          // [8][1024]
                   float* __restrict__ out) {               // [8192][1024] f32
    __shared__ __align__(16) unsigned short lds[2 * 32768];   // 128 KiB dbuf

    const int tid = threadIdx.x;
    const int bid = blockIdx.x;
    // XCD-pinned x-slices: xcd = bid&7 owns 4 b-tiles (2 MB x) L2-resident
    const int xcd = bid & 7;
    const int grp = bid >> 3;              // 0..127
    const int bt = xcd * 4 + (grp & 3);    // 0..31  b-tile
    const int ot = grp >> 2;               // 0..31  o-tile
    const int bbase = bt * 256;
    const int o_blk = ot * 32;

    const int w  = tid >> 6;           // wave 0..7 (2M x 4N), wave tile 128x64
    const int l  = tid & 63;
    const int lr = l & 15;
    const int lg = l >> 4;
    const int wrow = (w >> 2) * 128;
    const int wcol = (w & 3) * 64;

    // staging lane coords: chunk = 16 rows x 32 cols bf16 = 1024 B
    const int lrow = l >> 2;
    const int sg = (l & 3) ^ ((l >> 3) & 3);     // pre-swizzled col block (involution)
    const int swz = (lr >> 1) & 3;

    // fragment read offsets (ushort units), matching XOR involution
    int aoff[8][2], boff[4][2];
#pragma unroll
    for (int mf = 0; mf < 8; ++mf)
#pragma unroll
        for (int ks = 0; ks < 2; ++ks)
            aoff[mf][ks] = ks * 8192 + (wrow + mf * 16 + lr) * 32 + ((lg ^ swz) * 8);
#pragma unroll
    for (int nf = 0; nf < 4; ++nf)
#pragma unroll
        for (int ks = 0; ks < 2; ++ks)
            boff[nf][ks] = 16384 + ks * 8192 + (wcol + nf * 16 + lr) * 32 + ((lg ^ swz) * 8);

    // staging: 64 chunks/tile (A=W-gather ids 0-31, B=x ids 32-63), wave w owns 8
    auto stage4 = [&](int slot, int kt, int half) {
#pragma unroll
        for (int i = 0; i < 4; ++i) {
            const int id = w * 8 + half * 4 + i;
            unsigned short* dst = &lds[slot * 32768 + id * 512];
            const int sub = id & 15;
            const int col = kt * 64 + ((id >> 4) & 1) * 32 + sg * 8;
            if (id < 32) {
                // gathered row g = sub*16 + lrow: ke = lrow&7, o = o_blk + sub*2 + (lrow>>3)
                gload16(Wp + (size_t)(lrow & 7) * (NDIM * INDIM)
                           + (size_t)(o_blk + sub * 2 + (lrow >> 3)) * INDIM + col, dst);
            } else {
                gload16(xb + (size_t)(bbase + sub * 16 + lrow) * INDIM + col, dst);
            }
        }
    };

    f32x4 acc[8][4];
#pragma unroll
    for (int mf = 0; mf < 8; ++mf)
#pragma unroll
        for (int nf = 0; nf < 4; ++nf) acc[mf][nf] = f32x4{0.f, 0.f, 0.f, 0.f};

    stage4(0, 0, 0);
    stage4(0, 0, 1);

#pragma unroll 1
    for (int kt = 0; kt < 16; ++kt) {
        const int cs = kt & 1;
        const bool doS = (kt + 1) < 16;

        // tile gate: stage(kt) landed; barrier publishes all waves' staging.
        asm volatile("s_waitcnt vmcnt(0)\n\ts_barrier" ::: "memory");

        const unsigned short* lb = &lds[cs * 32768];
        short8 alo[4], ahi[4], b0[4], b1[4];

        // q0 operands + first staging batch + q1 A-frags (drain under q0 MFMA)
#pragma unroll
        for (int m = 0; m < 4; ++m) alo[m] = *(const short8*)(lb + aoff[m][0]);
#pragma unroll
        for (int n = 0; n < 4; ++n) b0[n] = *(const short8*)(lb + boff[n][0]);
        if (doS) stage4(cs ^ 1, kt + 1, 0);
#pragma unroll
        for (int m = 0; m < 4; ++m) ahi[m] = *(const short8*)(lb + aoff[4 + m][0]);

        __builtin_amdgcn_s_setprio(1);
#pragma unroll
        for (int m = 0; m < 4; ++m)
#pragma unroll
            for (int n = 0; n < 4; ++n)
                acc[m][n] = __builtin_amdgcn_mfma_f32_16x16x32_bf16(alo[m], b0[n], acc[m][n], 0, 0, 0);
        __builtin_amdgcn_s_setprio(0);

        // q2 operands (ks1) issued now; second staging batch
#pragma unroll
        for (int n = 0; n < 4; ++n) b1[n] = *(const short8*)(lb + boff[n][1]);
#pragma unroll
        for (int m = 0; m < 4; ++m) alo[m] = *(const short8*)(lb + aoff[m][1]);
        if (doS) stage4(cs ^ 1, kt + 1, 1);

        __builtin_amdgcn_s_setprio(1);
#pragma unroll
        for (int m = 0; m < 4; ++m)
#pragma unroll
            for (int n = 0; n < 4; ++n)
                acc[4 + m][n] = __builtin_amdgcn_mfma_f32_16x16x32_bf16(ahi[m], b0[n], acc[4 + m][n], 0, 0, 0);
        __builtin_amdgcn_s_setprio(0);

#pragma unroll
        for (int m = 0; m < 4; ++m) ahi[m] = *(const short8*)(lb + aoff[4 + m][1]);

        __builtin_amdgcn_s_setprio(1);
#pragma unroll
        for (int m = 0; m < 4; ++m)
#pragma unroll
            for (int n = 0; n < 4; ++n)
                acc[m][n] = __builtin_amdgcn_mfma_f32_16x16x32_bf16(alo[m], b1[n], acc[m][n], 0, 0, 0);
        __builtin_amdgcn_s_setprio(0);

        __builtin_amdgcn_s_setprio(1);
#pragma unroll
        for (int m = 0; m < 4; ++m)
#pragma unroll
            for (int n = 0; n < 4; ++n)
                acc[4 + m][n] = __builtin_amdgcn_mfma_f32_16x16x32_bf16(ahi[m], b1[n], acc[4 + m][n], 0, 0, 0);
        __builtin_amdgcn_s_setprio(0);
    }

    // ---- epilogue: per-frag k-blend (f32) -> LDS transpose -> coalesced store ----
    // C/D map: frag row = lg*4 + j -> g = wrow + mf*16 + lg*4 + j
    //          -> o = o_blk + (g>>3), k = g&7 = (lg&1)*4 + j
    __syncthreads();                       // staging consumed; reuse LDS
    float* ylds = (float*)lds;             // [256 b][36] f32 (144 B rows, 16-aligned)

    const int obw = wrow >> 3;             // wave o-offset: 0 or 16
#pragma unroll
    for (int nf = 0; nf < 4; ++nf) {
        const int bl = wcol + nf * 16 + lr;          // block-local b
        const float4 ea = *(const float4*)(ew + (size_t)(bbase + bl) * KEXP);
        const float4 eb = *(const float4*)(ew + (size_t)(bbase + bl) * KEXP + 4);
        float c0, c1, c2, c3;
        if (lg & 1) { c0 = eb.x; c1 = eb.y; c2 = eb.z; c3 = eb.w; }
        else        { c0 = ea.x; c1 = ea.y; c2 = ea.z; c3 = ea.w; }
#pragma unroll
        for (int mf = 0; mf < 8; ++mf) {
            float p = c0 * acc[mf][nf][0] + c1 * acc[mf][nf][1]
                    + c2 * acc[mf][nf][2] + c3 * acc[mf][nf][3];
            p += __shfl_xor(p, 16);                  // sum k 0-3 with k 4-7
            if (!(lg & 1))
                ylds[bl * 36 + obw + mf * 2 + (lg >> 1)] = p;
        }
    }
    __syncthreads();

    {   // coalesced f32 store + exact ew@bias
        const int b = tid >> 1;
        const int oh = (tid & 1) * 16;
        const float* yr = &ylds[b * 36 + oh];
        float y0[16];
#pragma unroll
        for (int jj = 0; jj < 16; ++jj) y0[jj] = yr[jj];
        const float4 ea = *(const float4*)(ew + (size_t)(bbase + b) * KEXP);
        const float4 e2 = *(const float4*)(ew + (size_t)(bbase + b) * KEXP + 4);
        const float ekk[8] = {ea.x, ea.y, ea.z, ea.w, e2.x, e2.y, e2.z, e2.w};
#pragma unroll
        for (int k = 0; k < 8; ++k) {
            const float* bp = bias + k * NDIM + o_blk + oh;
#pragma unroll
            for (int jj = 0; jj < 16; ++jj) y0[jj] += ekk[k] * bp[jj];
        }
        float* op = out + (size_t)(bbase + b) * NDIM + o_blk + oh;
#pragma unroll
        for (int jj = 0; jj < 4; ++jj)
            *(float4*)(op + jj * 4) =
                make_float4(y0[jj * 4], y0[jj * 4 + 1], y0[jj * 4 + 2], y0[jj * 4 + 3]);
    }
}

// ---------------- fallback (round-1 kernel, needs NO workspace) ----------------
#define FLDW 40
__global__ __launch_bounds__(256, 2)
void moe_blend_gemm_fb(const float* __restrict__ x, const float* __restrict__ ew,
                       const float* __restrict__ w, const float* __restrict__ bias,
                       float* __restrict__ out) {
    __shared__ unsigned short lA[128][FLDW];
    __shared__ unsigned short lB[128][FLDW];
    const int tid = threadIdx.x, bid = blockIdx.x;
    const int nt = bid & 7, mt = bid >> 3;
    const int mbase = mt * 128, nbase = nt * 128;
    const int trow = tid >> 1, tcol = (tid & 1) * 16;
    const float* xp = x + (size_t)(mbase + trow) * INDIM + tcol;
    const float* wp = w + (size_t)(nbase + trow) * INDIM + tcol;
    const float* ep = ew + (size_t)(mbase + trow) * KEXP;
    const int wid = tid >> 6, wrB = (wid >> 1) * 64, wcB = (wid & 1) * 64;
    const int l = tid & 63, lr = l & 15, lg = l >> 4;
    f32x4 acc[4][4];
#pragma unroll
    for (int m = 0; m < 4; ++m)
#pragma unroll
        for (int n = 0; n < 4; ++n) acc[m][n] = f32x4{0.f, 0.f, 0.f, 0.f};
    const unsigned short* rdA = &lA[wrB + lr][lg * 8];
    const unsigned short* rdB = &lB[wcB + lr][lg * 8];
    unsigned int* wA = (unsigned int*)&lA[trow][tcol];
    unsigned int* wB = (unsigned int*)&lB[trow][tcol];
    float4 ra0, ra1, ra2, ra3, rb0, rb1, rb2, rb3;
    float sc;
    {
        const float4* pa = (const float4*)(xp);
        ra0 = pa[0]; ra1 = pa[1]; ra2 = pa[2]; ra3 = pa[3];
        const float4* pb = (const float4*)(wp);
        rb0 = pb[0]; rb1 = pb[1]; rb2 = pb[2]; rb3 = pb[3];
        sc = ep[0];
    }
    for (int tt = 0; tt < 256; ++tt) {
        __syncthreads();
        uint4 qa0, qa1, qb0, qb1;
        qa0.x = pack2bf(ra0.x * sc, ra0.y * sc); qa0.y = pack2bf(ra0.z * sc, ra0.w * sc);
        qa0.z = pack2bf(ra1.x * sc, ra1.y * sc); qa0.w = pack2bf(ra1.z * sc, ra1.w * sc);
        qa1.x = pack2bf(ra2.x * sc, ra2.y * sc); qa1.y = pack2bf(ra2.z * sc, ra2.w * sc);
        qa1.z = pack2bf(ra3.x * sc, ra3.y * sc); qa1.w = pack2bf(ra3.z * sc, ra3.w * sc);
        qb0.x = pack2bf(rb0.x, rb0.y); qb0.y = pack2bf(rb0.z, rb0.w);
        qb0.z = pack2bf(rb1.x, rb1.y); qb0.w = pack2bf(rb1.z, rb1.w);
        qb1.x = pack2bf(rb2.x, rb2.y); qb1.y = pack2bf(rb2.z, rb2.w);
        qb1.z = pack2bf(rb3.x, rb3.y); qb1.w = pack2bf(rb3.z, rb3.w);
        *(uint4*)(wA) = qa0; *(uint4*)(wA + 4) = qa1;
        *(uint4*)(wB) = qb0; *(uint4*)(wB + 4) = qb1;
        __syncthreads();
        if (tt + 1 < 256) {
            const int kc = (tt + 1) >> 5, i0 = ((tt + 1) & 31) * 32;
            const float4* pa = (const float4*)(xp + i0);
            ra0 = pa[0]; ra1 = pa[1]; ra2 = pa[2]; ra3 = pa[3];
            const float4* pb = (const float4*)(wp + (size_t)kc * (size_t)(NDIM * INDIM) + i0);
            rb0 = pb[0]; rb1 = pb[1]; rb2 = pb[2]; rb3 = pb[3];
            sc = ep[kc];
        }
        short8 af[4], bf[4];
#pragma unroll
        for (int m = 0; m < 4; ++m) af[m] = *(const short8*)(rdA + m * 16 * FLDW);
#pragma unroll
        for (int n = 0; n < 4; ++n) bf[n] = *(const short8*)(rdB + n * 16 * FLDW);
#pragma unroll
        for (int m = 0; m < 4; ++m)
#pragma unroll
            for (int n = 0; n < 4; ++n)
                acc[m][n] = __builtin_amdgcn_mfma_f32_16x16x32_bf16(af[m], bf[n], acc[m][n], 0, 0, 0);
    }
#pragma unroll
    for (int m = 0; m < 4; ++m)
#pragma unroll
        for (int j = 0; j < 4; ++j) {
            const int gr = mbase + wrB + m * 16 + lg * 4 + j;
            const float4* e4 = (const float4*)(ew + (size_t)gr * KEXP);
            const float4 e0 = e4[0], e1 = e4[1];
            const float eb[8] = {e0.x, e0.y, e0.z, e0.w, e1.x, e1.y, e1.z, e1.w};
            float* op = out + (size_t)gr * NDIM + nbase + wcB;
#pragma unroll
            for (int n = 0; n < 4; ++n) {
                float t = acc[m][n][j];
#pragma unroll
                for (int kk = 0; kk < 8; ++kk) t += eb[kk] * bias[kk * NDIM + nbase + wcB + n * 16 + lr];
                op[n * 16 + lr] = t;
            }
        }
}

extern "C" void kernel_launch(void* const* d_in, const int* in_sizes, int n_in,
                              void* d_out, int out_size, void* d_ws, size_t ws_size,
                              hipStream_t stream) {
    (void)in_sizes; (void)n_in; (void)out_size;
    const float* x    = (const float*)d_in[0];
    const float* ew   = (const float*)d_in[1];
    const float* w    = (const float*)d_in[2];
    const float* bias = (const float*)d_in[3];
    float* out = (float*)d_out;

    const size_t need = (size_t)(NX + NW) * sizeof(unsigned short);   // 33.5 MB

    if (ws_size >= need) {
        unsigned short* xb = (unsigned short*)d_ws;
        unsigned short* Wp = xb + NX;
        hipLaunchKernelGGL(convert_bf16, dim3(4096), dim3(256), 0, stream, x, w, xb);
        hipLaunchKernelGGL(moe_gemm_fold, dim3(1024), dim3(512), 0, stream, xb, ew, Wp, bias, out);
    } else {
        hipLaunchKernelGGL(moe_blend_gemm_fb, dim3(512), dim3(256), 0, stream, x, ew, w, bias, out);
    }
}